// Round 15
// baseline (155.378 us; speedup 1.0000x reference)
//
#include <hip/hip_runtime.h>
#include <cstdint>
#include <cstddef>

// GNNEncoder: 2x (edge-MLP GNN layer) + mean pool + MLP head. bf16 node pipeline.
// R15: col2 scatter via NON-TEMPORAL stores (bypass L2 -> no partial-line
// write-allocate/bounce; R14 showed 41MB of writeback amplification for 1.25MB
// of ticket data). Edge streams nt-loaded (read-once). Otherwise R14 structure:
// setup -> fill||GEMM1 -> agg1 -> layer(H1+AB2) -> agg2 -> H2+pool -> head.

static constexpr int GRAPHS = 64;
static constexpr int PADC = 4;     // ints per padded counter slot (16 B)
static constexpr int CAP = 64;     // ELL row capacity (deg ~ Poisson(16); P(>64)~3e-22)

using bf16x8 = __attribute__((ext_vector_type(8))) short;
using f32x4 = __attribute__((ext_vector_type(4))) float;

__device__ inline float bf2f(uint u) { return __builtin_bit_cast(float, u << 16); }
__device__ inline float bf2f_hi(uint u) { return __builtin_bit_cast(float, u & 0xffff0000u); }
__device__ inline ushort f2bf(float f) {
    uint u = __builtin_bit_cast(uint, f);
    return (ushort)((u + 0x7fffu + ((u >> 16) & 1u)) >> 16);
}

union SM {
    uint4 xt[64 * 17];               // node tile, padded row stride 17*16B
    struct { float p[128]; float h[128]; } hd;
};

// ---------------- shared device bodies ----------------
template <bool F32IN>
__device__ __forceinline__ void stage_tile(SM& sm, const void* Xin, int node0) {
    int t = threadIdx.x;
    int row = t >> 2;
#pragma unroll
    for (int i = 0; i < 4; ++i) {
        int chunk = (t & 3) + i * 4;
        uint4 v;
        if constexpr (F32IN) {
            const float* s = (const float*)Xin + (size_t)(node0 + row) * 128 + chunk * 8;
            float4 v0 = *reinterpret_cast<const float4*>(s);
            float4 v1 = *reinterpret_cast<const float4*>(s + 4);
            uint* vu = reinterpret_cast<uint*>(&v);
            vu[0] = (uint)f2bf(v0.x) | ((uint)f2bf(v0.y) << 16);
            vu[1] = (uint)f2bf(v0.z) | ((uint)f2bf(v0.w) << 16);
            vu[2] = (uint)f2bf(v1.x) | ((uint)f2bf(v1.y) << 16);
            vu[3] = (uint)f2bf(v1.z) | ((uint)f2bf(v1.w) << 16);
        } else {
            v = *reinterpret_cast<const uint4*>((const ushort*)Xin + (size_t)(node0 + row) * 128 + chunk * 8);
        }
        sm.xt[row * 17 + chunk] = v;
    }
}

template <int NOUT, bool RELU, bool DEGBIAS>
__device__ __forceinline__ void ngemm_compute(SM& sm, const ushort* Wt, const float* bias,
                                              const int* degp, ushort* Y, int node0) {
    int t = threadIdx.x;
    int lane = t & 63, wv = t >> 6;
    int lr = lane & 15, lg = lane >> 4;

    bf16x8 bfr[4][4];
#pragma unroll
    for (int rs = 0; rs < 4; ++rs)
#pragma unroll
        for (int kk = 0; kk < 4; ++kk)
            bfr[rs][kk] = *reinterpret_cast<const bf16x8*>(&sm.xt[(rs * 16 + lr) * 17 + lg + 4 * kk]);

    float degf[4];
    if constexpr (DEGBIAS) {
#pragma unroll
        for (int rs = 0; rs < 4; ++rs) {
            int r_ = node0 + rs * 16 + lr;
            degf[rs] = (float)degp[r_ * PADC];
        }
    }

    constexpr int NBW = NOUT / 64;
#pragma unroll
    for (int q = 0; q < NBW; ++q) {
        int nb = wv * NBW + q;
        const ushort* wrow = Wt + (size_t)(nb * 16 + lr) * 128 + lg * 8;
        bf16x8 af[4];
#pragma unroll
        for (int kk = 0; kk < 4; ++kk) af[kk] = *reinterpret_cast<const bf16x8*>(wrow + kk * 32);
        float4 bb = *reinterpret_cast<const float4*>(bias + nb * 16 + lg * 4);
        const float* bbp = reinterpret_cast<const float*>(&bb);
#pragma unroll
        for (int rs = 0; rs < 4; ++rs) {
            f32x4 acc = {0.f, 0.f, 0.f, 0.f};
#pragma unroll
            for (int kk = 0; kk < 4; ++kk)
                acc = __builtin_amdgcn_mfma_f32_16x16x32_bf16(af[kk], bfr[rs][kk], acc, 0, 0, 0);
            ushort4 o;
#pragma unroll
            for (int r = 0; r < 4; ++r) {
                float v = acc[r] + (DEGBIAS ? degf[rs] * bbp[r] : bbp[r]);
                if constexpr (RELU) v = fmaxf(v, 0.f);
                reinterpret_cast<ushort*>(&o)[r] = f2bf(v);
            }
            *reinterpret_cast<ushort4*>(Y + (size_t)(node0 + rs * 16 + lr) * NOUT + nb * 16 + lg * 4) = o;
        }
    }
}

template <int NOUT, bool RELU, bool DEGBIAS, bool F32IN>
__device__ __forceinline__ void ngemm_tile(SM& sm, const void* Xin, const ushort* Wt,
                                           const float* bias, const int* degp, ushort* Y, int node0) {
    stage_tile<F32IN>(sm, Xin, node0);
    __syncthreads();
    ngemm_compute<NOUT, RELU, DEGBIAS>(sm, Wt, bias, degp, Y, node0);
}

// fused: H1 = relu(Hagg@W2t^T + deg*b2) in regs -> LDS -> AB2 = H1@W1n^T + bn
__device__ __forceinline__ void layer_tile(SM& sm, const ushort* Hagg,
                                           const ushort* W2t, const float* b2,
                                           const ushort* W1n, const float* bn,
                                           const int* degp, ushort* AB2, int node0) {
    stage_tile<false>(sm, Hagg, node0);
    __syncthreads();
    int t = threadIdx.x;
    int lane = t & 63, wv = t >> 6;
    int lr = lane & 15, lg = lane >> 4;

    bf16x8 bfr[4][4];
#pragma unroll
    for (int rs = 0; rs < 4; ++rs)
#pragma unroll
        for (int kk = 0; kk < 4; ++kk)
            bfr[rs][kk] = *reinterpret_cast<const bf16x8*>(&sm.xt[(rs * 16 + lr) * 17 + lg + 4 * kk]);

    float degf[4];
#pragma unroll
    for (int rs = 0; rs < 4; ++rs) {
        int r_ = node0 + rs * 16 + lr;
        degf[rs] = (float)degp[r_ * PADC];
    }

    ushort4 h1o[2][4];
#pragma unroll
    for (int q = 0; q < 2; ++q) {
        int nb = wv * 2 + q;
        const ushort* wrow = W2t + (size_t)(nb * 16 + lr) * 128 + lg * 8;
        bf16x8 af[4];
#pragma unroll
        for (int kk = 0; kk < 4; ++kk) af[kk] = *reinterpret_cast<const bf16x8*>(wrow + kk * 32);
        float4 bb = *reinterpret_cast<const float4*>(b2 + nb * 16 + lg * 4);
        const float* bbp = reinterpret_cast<const float*>(&bb);
#pragma unroll
        for (int rs = 0; rs < 4; ++rs) {
            f32x4 acc = {0.f, 0.f, 0.f, 0.f};
#pragma unroll
            for (int kk = 0; kk < 4; ++kk)
                acc = __builtin_amdgcn_mfma_f32_16x16x32_bf16(af[kk], bfr[rs][kk], acc, 0, 0, 0);
#pragma unroll
            for (int r = 0; r < 4; ++r) {
                float v = fmaxf(acc[r] + degf[rs] * bbp[r], 0.f);
                reinterpret_cast<ushort*>(&h1o[q][rs])[r] = f2bf(v);
            }
        }
    }
    __syncthreads();
    char* xb = reinterpret_cast<char*>(sm.xt);
#pragma unroll
    for (int q = 0; q < 2; ++q)
#pragma unroll
        for (int rs = 0; rs < 4; ++rs) {
            int row = rs * 16 + lr;
            int colc = (wv * 2 + q) * 16 + lg * 4;
            *reinterpret_cast<ushort4*>(xb + row * 272 + (colc >> 3) * 16 + (colc & 7) * 2) = h1o[q][rs];
        }
    __syncthreads();
    ngemm_compute<256, false, false>(sm, W1n, bn, nullptr, AB2, node0);
}

__device__ __forceinline__ void accum8(uint4 b, const float2* a, float2* acc) {
    const uint* bu = reinterpret_cast<const uint*>(&b);
#pragma unroll
    for (int j = 0; j < 4; ++j) {
        uint u = bu[j];
        acc[j].x += fmaxf(a[j].x + bf2f(u), 0.f);
        acc[j].y += fmaxf(a[j].y + bf2f_hi(u), 0.f);
    }
}

// ELL aggregation: edges for node n live at col2[n*CAP .. n*CAP+deg) (ushort ids)
__device__ __forceinline__ void agg_node(const ushort* AB, const int* degp, const ushort* col2,
                                         ushort* Hagg, int n, int lane) {
    int fs = lane & 15;
    int lg = lane >> 4;
    uint4 av = *reinterpret_cast<const uint4*>(AB + (size_t)n * 256 + fs * 8);
    float2 a[4];
    {
        const uint* au = reinterpret_cast<const uint*>(&av);
#pragma unroll
        for (int j = 0; j < 4; ++j) a[j] = make_float2(bf2f(au[j]), bf2f_hi(au[j]));
    }
    float2 acc[4] = {{0.f, 0.f}, {0.f, 0.f}, {0.f, 0.f}, {0.f, 0.f}};
    const ushort* cb = col2 + (size_t)n * CAP;
    int deg = degp[n * PADC];
    int eMain = deg & ~7;
    for (int eb = 0; eb < eMain; eb += 8) {
        int sA = cb[eb + lg];
        int sB = cb[eb + lg + 4];
        uint4 bA = *reinterpret_cast<const uint4*>(AB + (size_t)sA * 256 + 128 + fs * 8);
        uint4 bB = *reinterpret_cast<const uint4*>(AB + (size_t)sB * 256 + 128 + fs * 8);
        accum8(bA, a, acc);
        accum8(bB, a, acc);
    }
    for (int e = eMain + lg; e < deg; e += 4) {
        int s = cb[e];
        uint4 b = *reinterpret_cast<const uint4*>(AB + (size_t)s * 256 + 128 + fs * 8);
        accum8(b, a, acc);
    }
#pragma unroll
    for (int j = 0; j < 4; ++j) {
        acc[j].x += __shfl_xor(acc[j].x, 16);
        acc[j].y += __shfl_xor(acc[j].y, 16);
        acc[j].x += __shfl_xor(acc[j].x, 32);
        acc[j].y += __shfl_xor(acc[j].y, 32);
    }
    if (lg == 0) {
        uint4 o;
        uint* ou = reinterpret_cast<uint*>(&o);
#pragma unroll
        for (int j = 0; j < 4; ++j)
            ou[j] = (uint)f2bf(acc[j].x) | ((uint)f2bf(acc[j].y) << 16);
        *reinterpret_cast<uint4*>(Hagg + (size_t)n * 128 + fs * 8) = o;
    }
}

// ---------------- kernels ----------------
__global__ __launch_bounds__(256) void setup_k(
    const float* __restrict__ w1_1, const float* __restrict__ w2_1,
    const float* __restrict__ w1_2, const float* __restrict__ w2_2,
    const float* __restrict__ b1_1, const float* __restrict__ b2_1,
    ushort* __restrict__ wt1a, ushort* __restrict__ wt1b,
    ushort* __restrict__ wt2a, ushort* __restrict__ wt2b,
    float* __restrict__ b256_1, float* __restrict__ b256_2,
    int* __restrict__ degp, float* __restrict__ psum,
    const int* __restrict__ batch, int* __restrict__ gs, int M, int nbDeg) {
    int b = blockIdx.x, t = threadIdx.x;
    if (b < 128) {
        int i = b * 256 + t;
        int j = i >> 7, k = i & 127;
        wt1a[i] = f2bf((j < 128) ? w1_1[k * 128 + j] : w1_1[(128 + k) * 128 + (j - 128)]);
        wt1b[i] = f2bf((j < 128) ? w2_1[k * 128 + j] : w2_1[(128 + k) * 128 + (j - 128)]);
        return;
    }
    b -= 128;
    if (b < 64) {
        int i = b * 256 + t;
        int j = i >> 7, k = i & 127;
        wt2a[i] = f2bf(w1_2[k * 128 + j]);
        wt2b[i] = f2bf(w2_2[k * 128 + j]);
        return;
    }
    b -= 64;
    if (b < nbDeg) {
        int i = b * 256 + t;
        if (i < M) *reinterpret_cast<int4*>(degp + i * PADC) = make_int4(0, 0, 0, 0);
        return;
    }
    b -= nbDeg;
    if (b < 32) {
        psum[b * 256 + t] = 0.f;
        return;
    }
    b -= 32;
    if (b == 0) {
        b256_1[t] = (t < 128) ? b1_1[t] : 0.f;
        b256_2[t] = (t < 128) ? b2_1[t] : 0.f;
        return;
    }
    if (t > GRAPHS) return;
    int lo = 0, hi = M;
    while (lo < hi) {
        int mid = (lo + hi) >> 1;
        if (batch[mid] < t) lo = mid + 1;
        else hi = mid;
    }
    gs[t] = lo;
}

// ELL fill (blocks [0,FB)) in parallel with layer1 edge-GEMM (blocks [FB, FB+M/64))
// col2 stores are NON-TEMPORAL (bypass L2: kill partial-line writeback bounce).
__global__ __launch_bounds__(256) void fillgemm_k(const int* __restrict__ src, const int* __restrict__ dst,
                                                  int* __restrict__ degp, ushort* __restrict__ col2,
                                                  int E, int FB,
                                                  const float* __restrict__ x,
                                                  const ushort* __restrict__ wt1a,
                                                  const float* __restrict__ b256_1,
                                                  ushort* __restrict__ AB1) {
    __shared__ SM sm;
    int b = blockIdx.x;
    if (b < FB) {
        for (int i = b * 256 + threadIdx.x; i < E; i += FB * 256) {
            int d = __builtin_nontemporal_load(&dst[i]);
            int s = __builtin_nontemporal_load(&src[i]);
            int ticket = atomicAdd(&degp[d * PADC], 1);
            if (ticket < CAP)
                __builtin_nontemporal_store((ushort)s, &col2[(size_t)d * CAP + ticket]);
        }
        return;
    }
    ngemm_tile<256, false, false, true>(sm, x, wt1a, b256_1, nullptr, AB1, (b - FB) * 64);
}

__global__ __launch_bounds__(256) void agg_g(const ushort* __restrict__ AB, const int* __restrict__ degp,
                                             const ushort* __restrict__ col2, ushort* __restrict__ Hagg,
                                             int M) {
    int lane = threadIdx.x & 63, wv = threadIdx.x >> 6;
    int n = blockIdx.x * 4 + wv;
    if (n < M) agg_node(AB, degp, col2, Hagg, n, lane);
}

__global__ __launch_bounds__(256) void layer_g(const ushort* __restrict__ Hagg,
                                               const ushort* __restrict__ W2t, const float* __restrict__ b2,
                                               const ushort* __restrict__ W1n, const float* __restrict__ bn,
                                               const int* __restrict__ degp, ushort* __restrict__ AB2) {
    __shared__ SM sm;
    layer_tile(sm, Hagg, W2t, b2, W1n, bn, degp, AB2, blockIdx.x * 64);
}

// H2-GEMM + fused mean-pool partials (two-accumulator boundary handling).
__global__ __launch_bounds__(256) void h2pool_k(const ushort* __restrict__ Hagg,
                                                const ushort* __restrict__ Wt, const float* __restrict__ bias,
                                                const int* __restrict__ degp, const int* __restrict__ batch,
                                                float* __restrict__ psum) {
    __shared__ SM sm;
    int node0 = blockIdx.x * 64;
    stage_tile<false>(sm, Hagg, node0);
    __syncthreads();

    int t = threadIdx.x;
    int lane = t & 63, wv = t >> 6;
    int lr = lane & 15, lg = lane >> 4;

    bf16x8 bfr[4][4];
#pragma unroll
    for (int rs = 0; rs < 4; ++rs)
#pragma unroll
        for (int kk = 0; kk < 4; ++kk)
            bfr[rs][kk] = *reinterpret_cast<const bf16x8*>(&sm.xt[(rs * 16 + lr) * 17 + lg + 4 * kk]);

    float degf[4];
    int gnode[4];
#pragma unroll
    for (int rs = 0; rs < 4; ++rs) {
        int r_ = node0 + rs * 16 + lr;
        degf[rs] = (float)degp[r_ * PADC];
        gnode[rs] = batch[r_];
    }

    int gLo = batch[node0], gHi = batch[node0 + 63];
    bool two = (gHi - gLo) <= 1;

    float sLo[2][4], sHi[2][4];
#pragma unroll
    for (int q = 0; q < 2; ++q)
#pragma unroll
        for (int r = 0; r < 4; ++r) { sLo[q][r] = 0.f; sHi[q][r] = 0.f; }

#pragma unroll
    for (int q = 0; q < 2; ++q) {
        int nb = wv * 2 + q;
        const ushort* wrow = Wt + (size_t)(nb * 16 + lr) * 128 + lg * 8;
        bf16x8 af[4];
#pragma unroll
        for (int kk = 0; kk < 4; ++kk) af[kk] = *reinterpret_cast<const bf16x8*>(wrow + kk * 32);
        float4 bb = *reinterpret_cast<const float4*>(bias + nb * 16 + lg * 4);
        const float* bbp = reinterpret_cast<const float*>(&bb);
#pragma unroll
        for (int rs = 0; rs < 4; ++rs) {
            f32x4 acc = {0.f, 0.f, 0.f, 0.f};
#pragma unroll
            for (int kk = 0; kk < 4; ++kk)
                acc = __builtin_amdgcn_mfma_f32_16x16x32_bf16(af[kk], bfr[rs][kk], acc, 0, 0, 0);
            if (two) {
                bool isLo = (gnode[rs] == gLo);
#pragma unroll
                for (int r = 0; r < 4; ++r) {
                    float v = fmaxf(acc[r] + degf[rs] * bbp[r], 0.f);
                    if (isLo) sLo[q][r] += v;
                    else      sHi[q][r] += v;
                }
            } else {
#pragma unroll
                for (int r = 0; r < 4; ++r) {
                    float v = fmaxf(acc[r] + degf[rs] * bbp[r], 0.f);
                    atomicAdd(&psum[gnode[rs] * 128 + nb * 16 + lg * 4 + r], v);
                }
            }
        }
    }
    if (two) {
        bool split = (gHi != gLo);
#pragma unroll
        for (int q = 0; q < 2; ++q)
#pragma unroll
            for (int r = 0; r < 4; ++r) {
#pragma unroll
                for (int d = 1; d <= 8; d <<= 1) {
                    sLo[q][r] += __shfl_xor(sLo[q][r], d);
                    if (split) sHi[q][r] += __shfl_xor(sHi[q][r], d);
                }
            }
        if (lr == 0) {
#pragma unroll
            for (int q = 0; q < 2; ++q)
#pragma unroll
                for (int r = 0; r < 4; ++r) {
                    int f = (wv * 2 + q) * 16 + lg * 4 + r;
                    atomicAdd(&psum[gLo * 128 + f], sLo[q][r]);
                    if (split) atomicAdd(&psum[gHi * 128 + f], sHi[q][r]);
                }
        }
    }
}

__global__ __launch_bounds__(256) void head_g(const float* __restrict__ psum, const int* __restrict__ gs,
                                              const float* __restrict__ wm1, const float* __restrict__ bm1,
                                              const float* __restrict__ wm2, const float* __restrict__ bm2,
                                              float* __restrict__ out) {
    __shared__ SM sm;
    int g = blockIdx.x, t = threadIdx.x;
    int cnt = gs[g + 1] - gs[g];
    float rcp = 1.0f / (float)(cnt > 0 ? cnt : 1);
    if (t < 128) sm.hd.p[t] = psum[g * 128 + t] * rcp;
    __syncthreads();
    if (t < 128) {
        float a = bm1[t];
        for (int k = 0; k < 128; ++k) a += sm.hd.p[k] * wm1[k * 128 + t];
        sm.hd.h[t] = fmaxf(a, 0.f);
    }
    __syncthreads();
    if (t < 128) {
        float acc[4];
#pragma unroll
        for (int j = 0; j < 4; ++j) acc[j] = bm2[j * 128 + t];
        for (int k = 0; k < 128; ++k) {
            float hv = sm.hd.h[k];
#pragma unroll
            for (int j = 0; j < 4; ++j) acc[j] += hv * wm2[k * 512 + j * 128 + t];
        }
#pragma unroll
        for (int j = 0; j < 4; ++j) out[(size_t)g * 512 + j * 128 + t] = acc[j];
    }
}

extern "C" void kernel_launch(void* const* d_in, const int* in_sizes, int n_in,
                              void* d_out, int out_size, void* d_ws, size_t ws_size,
                              hipStream_t stream) {
    const float* x = (const float*)d_in[0];
    const int* ei = (const int*)d_in[1];
    const int* batch = (const int*)d_in[2];
    const float* w1_1 = (const float*)d_in[3];
    const float* b1_1 = (const float*)d_in[4];
    const float* w1_2 = (const float*)d_in[5];
    const float* b1_2 = (const float*)d_in[6];
    const float* w2_1 = (const float*)d_in[7];
    const float* b2_1 = (const float*)d_in[8];
    const float* w2_2 = (const float*)d_in[9];
    const float* b2_2 = (const float*)d_in[10];
    const float* wm1 = (const float*)d_in[11];
    const float* bm1 = (const float*)d_in[12];
    const float* wm2 = (const float*)d_in[13];
    const float* bm2 = (const float*)d_in[14];

    const int E = in_sizes[1] / 2;
    const int M = in_sizes[0] / 128;
    const int* srcp = ei;
    const int* dstp = ei + E;

    char* ws = (char*)d_ws;
    size_t off = 0;
    auto alloc = [&](size_t bytes) -> void* {
        void* ptr = ws + off;
        off += (bytes + 255) & ~(size_t)255;
        return ptr;
    };
    ushort* AB1 = (ushort*)alloc((size_t)M * 256 * 2);
    ushort* AB2 = (ushort*)alloc((size_t)M * 256 * 2);
    ushort* Hagg = (ushort*)alloc((size_t)M * 128 * 2);
    int* degp = (int*)alloc((size_t)M * PADC * 4);      // padded deg/ticket counters
    ushort* col2 = (ushort*)alloc((size_t)M * CAP * 2); // ELL adjacency (ushort ids)
    int* gs = (int*)alloc((GRAPHS + 1) * 4);
    float* psum = (float*)alloc(GRAPHS * 128 * 4);
    ushort* wt1a = (ushort*)alloc(256 * 128 * 2);
    ushort* wt1b = (ushort*)alloc(256 * 128 * 2);
    ushort* wt2a = (ushort*)alloc(128 * 128 * 2);
    ushort* wt2b = (ushort*)alloc(128 * 128 * 2);
    float* b256_1 = (float*)alloc(256 * 4);
    float* b256_2 = (float*)alloc(256 * 4);

    const int nbDeg = (M + 255) / 256;
    const int FB = 1024;

    // 1. setup (weights, degp=0, psum=0, biases, gstart)
    setup_k<<<128 + 64 + nbDeg + 32 + 2, 256, 0, stream>>>(
        w1_1, w2_1, w1_2, w2_2, b1_1, b2_1, wt1a, wt1b, wt2a, wt2b, b256_1, b256_2,
        degp, psum, batch, gs, M, nbDeg);
    // 2. ELL fill || layer1 edge-GEMM
    fillgemm_k<<<FB + M / 64, 256, 0, stream>>>(srcp, dstp, degp, col2, E, FB, x, wt1a, b256_1, AB1);
    // 3. agg layer1
    agg_g<<<(M + 3) / 4, 256, 0, stream>>>(AB1, degp, col2, Hagg, M);
    // 4. fused H1-GEMM + layer2 edge-GEMM
    layer_g<<<M / 64, 256, 0, stream>>>(Hagg, wt2a, b1_2, wt1b, b256_2, degp, AB2);
    // 5. agg layer2
    agg_g<<<(M + 3) / 4, 256, 0, stream>>>(AB2, degp, col2, Hagg, M);
    // 6. H2-GEMM + fused pool
    h2pool_k<<<M / 64, 256, 0, stream>>>(Hagg, wt2b, b2_2, degp, batch, psum);
    // 7. head
    head_g<<<GRAPHS, 256, 0, stream>>>(psum, gs, wm1, bm1, wm2, bm2, (float*)d_out);
}

// Round 16
// 143.665 us; speedup vs baseline: 1.0815x; 1.0815x over previous
//
#include <hip/hip_runtime.h>
#include <cstdint>
#include <cstddef>

// GNNEncoder: 2x (edge-MLP GNN layer) + mean pool + MLP head. bf16 node pipeline.
// R16: XCD-partitioned ELL fill. Fill block-group s (blockIdx%8, dispatch
// round-robin ~ XCD id) scans ALL edges, commits only dst in node-range s ->
// every degp/col2 line has a single writer XCD: no cross-XCD line migration
// (R14/R15 evidence: 41MB writeback amplification, nt-immune). 8x edge-stream
// reads (~40MB streaming) is the cheap price. 7 dispatches as R14.

static constexpr int GRAPHS = 64;
static constexpr int PADC = 4;     // ints per padded counter slot (16 B)
static constexpr int CAP = 64;     // ELL row capacity (deg ~ Poisson(16); P(>64)~3e-22)

using bf16x8 = __attribute__((ext_vector_type(8))) short;
using f32x4 = __attribute__((ext_vector_type(4))) float;

__device__ inline float bf2f(uint u) { return __builtin_bit_cast(float, u << 16); }
__device__ inline float bf2f_hi(uint u) { return __builtin_bit_cast(float, u & 0xffff0000u); }
__device__ inline ushort f2bf(float f) {
    uint u = __builtin_bit_cast(uint, f);
    return (ushort)((u + 0x7fffu + ((u >> 16) & 1u)) >> 16);
}

union SM {
    uint4 xt[64 * 17];               // node tile, padded row stride 17*16B
    struct { float p[128]; float h[128]; } hd;
};

// ---------------- shared device bodies ----------------
template <bool F32IN>
__device__ __forceinline__ void stage_tile(SM& sm, const void* Xin, int node0) {
    int t = threadIdx.x;
    int row = t >> 2;
#pragma unroll
    for (int i = 0; i < 4; ++i) {
        int chunk = (t & 3) + i * 4;
        uint4 v;
        if constexpr (F32IN) {
            const float* s = (const float*)Xin + (size_t)(node0 + row) * 128 + chunk * 8;
            float4 v0 = *reinterpret_cast<const float4*>(s);
            float4 v1 = *reinterpret_cast<const float4*>(s + 4);
            uint* vu = reinterpret_cast<uint*>(&v);
            vu[0] = (uint)f2bf(v0.x) | ((uint)f2bf(v0.y) << 16);
            vu[1] = (uint)f2bf(v0.z) | ((uint)f2bf(v0.w) << 16);
            vu[2] = (uint)f2bf(v1.x) | ((uint)f2bf(v1.y) << 16);
            vu[3] = (uint)f2bf(v1.z) | ((uint)f2bf(v1.w) << 16);
        } else {
            v = *reinterpret_cast<const uint4*>((const ushort*)Xin + (size_t)(node0 + row) * 128 + chunk * 8);
        }
        sm.xt[row * 17 + chunk] = v;
    }
}

template <int NOUT, bool RELU, bool DEGBIAS>
__device__ __forceinline__ void ngemm_compute(SM& sm, const ushort* Wt, const float* bias,
                                              const int* degp, ushort* Y, int node0) {
    int t = threadIdx.x;
    int lane = t & 63, wv = t >> 6;
    int lr = lane & 15, lg = lane >> 4;

    bf16x8 bfr[4][4];
#pragma unroll
    for (int rs = 0; rs < 4; ++rs)
#pragma unroll
        for (int kk = 0; kk < 4; ++kk)
            bfr[rs][kk] = *reinterpret_cast<const bf16x8*>(&sm.xt[(rs * 16 + lr) * 17 + lg + 4 * kk]);

    float degf[4];
    if constexpr (DEGBIAS) {
#pragma unroll
        for (int rs = 0; rs < 4; ++rs) {
            int r_ = node0 + rs * 16 + lr;
            degf[rs] = (float)degp[r_ * PADC];
        }
    }

    constexpr int NBW = NOUT / 64;
#pragma unroll
    for (int q = 0; q < NBW; ++q) {
        int nb = wv * NBW + q;
        const ushort* wrow = Wt + (size_t)(nb * 16 + lr) * 128 + lg * 8;
        bf16x8 af[4];
#pragma unroll
        for (int kk = 0; kk < 4; ++kk) af[kk] = *reinterpret_cast<const bf16x8*>(wrow + kk * 32);
        float4 bb = *reinterpret_cast<const float4*>(bias + nb * 16 + lg * 4);
        const float* bbp = reinterpret_cast<const float*>(&bb);
#pragma unroll
        for (int rs = 0; rs < 4; ++rs) {
            f32x4 acc = {0.f, 0.f, 0.f, 0.f};
#pragma unroll
            for (int kk = 0; kk < 4; ++kk)
                acc = __builtin_amdgcn_mfma_f32_16x16x32_bf16(af[kk], bfr[rs][kk], acc, 0, 0, 0);
            ushort4 o;
#pragma unroll
            for (int r = 0; r < 4; ++r) {
                float v = acc[r] + (DEGBIAS ? degf[rs] * bbp[r] : bbp[r]);
                if constexpr (RELU) v = fmaxf(v, 0.f);
                reinterpret_cast<ushort*>(&o)[r] = f2bf(v);
            }
            *reinterpret_cast<ushort4*>(Y + (size_t)(node0 + rs * 16 + lr) * NOUT + nb * 16 + lg * 4) = o;
        }
    }
}

template <int NOUT, bool RELU, bool DEGBIAS, bool F32IN>
__device__ __forceinline__ void ngemm_tile(SM& sm, const void* Xin, const ushort* Wt,
                                           const float* bias, const int* degp, ushort* Y, int node0) {
    stage_tile<F32IN>(sm, Xin, node0);
    __syncthreads();
    ngemm_compute<NOUT, RELU, DEGBIAS>(sm, Wt, bias, degp, Y, node0);
}

// fused: H1 = relu(Hagg@W2t^T + deg*b2) in regs -> LDS -> AB2 = H1@W1n^T + bn
__device__ __forceinline__ void layer_tile(SM& sm, const ushort* Hagg,
                                           const ushort* W2t, const float* b2,
                                           const ushort* W1n, const float* bn,
                                           const int* degp, ushort* AB2, int node0) {
    stage_tile<false>(sm, Hagg, node0);
    __syncthreads();
    int t = threadIdx.x;
    int lane = t & 63, wv = t >> 6;
    int lr = lane & 15, lg = lane >> 4;

    bf16x8 bfr[4][4];
#pragma unroll
    for (int rs = 0; rs < 4; ++rs)
#pragma unroll
        for (int kk = 0; kk < 4; ++kk)
            bfr[rs][kk] = *reinterpret_cast<const bf16x8*>(&sm.xt[(rs * 16 + lr) * 17 + lg + 4 * kk]);

    float degf[4];
#pragma unroll
    for (int rs = 0; rs < 4; ++rs) {
        int r_ = node0 + rs * 16 + lr;
        degf[rs] = (float)degp[r_ * PADC];
    }

    ushort4 h1o[2][4];
#pragma unroll
    for (int q = 0; q < 2; ++q) {
        int nb = wv * 2 + q;
        const ushort* wrow = W2t + (size_t)(nb * 16 + lr) * 128 + lg * 8;
        bf16x8 af[4];
#pragma unroll
        for (int kk = 0; kk < 4; ++kk) af[kk] = *reinterpret_cast<const bf16x8*>(wrow + kk * 32);
        float4 bb = *reinterpret_cast<const float4*>(b2 + nb * 16 + lg * 4);
        const float* bbp = reinterpret_cast<const float*>(&bb);
#pragma unroll
        for (int rs = 0; rs < 4; ++rs) {
            f32x4 acc = {0.f, 0.f, 0.f, 0.f};
#pragma unroll
            for (int kk = 0; kk < 4; ++kk)
                acc = __builtin_amdgcn_mfma_f32_16x16x32_bf16(af[kk], bfr[rs][kk], acc, 0, 0, 0);
#pragma unroll
            for (int r = 0; r < 4; ++r) {
                float v = fmaxf(acc[r] + degf[rs] * bbp[r], 0.f);
                reinterpret_cast<ushort*>(&h1o[q][rs])[r] = f2bf(v);
            }
        }
    }
    __syncthreads();
    char* xb = reinterpret_cast<char*>(sm.xt);
#pragma unroll
    for (int q = 0; q < 2; ++q)
#pragma unroll
        for (int rs = 0; rs < 4; ++rs) {
            int row = rs * 16 + lr;
            int colc = (wv * 2 + q) * 16 + lg * 4;
            *reinterpret_cast<ushort4*>(xb + row * 272 + (colc >> 3) * 16 + (colc & 7) * 2) = h1o[q][rs];
        }
    __syncthreads();
    ngemm_compute<256, false, false>(sm, W1n, bn, nullptr, AB2, node0);
}

__device__ __forceinline__ void accum8(uint4 b, const float2* a, float2* acc) {
    const uint* bu = reinterpret_cast<const uint*>(&b);
#pragma unroll
    for (int j = 0; j < 4; ++j) {
        uint u = bu[j];
        acc[j].x += fmaxf(a[j].x + bf2f(u), 0.f);
        acc[j].y += fmaxf(a[j].y + bf2f_hi(u), 0.f);
    }
}

// ELL aggregation: edges for node n live at col2[n*CAP .. n*CAP+deg) (ushort ids)
__device__ __forceinline__ void agg_node(const ushort* AB, const int* degp, const ushort* col2,
                                         ushort* Hagg, int n, int lane) {
    int fs = lane & 15;
    int lg = lane >> 4;
    uint4 av = *reinterpret_cast<const uint4*>(AB + (size_t)n * 256 + fs * 8);
    float2 a[4];
    {
        const uint* au = reinterpret_cast<const uint*>(&av);
#pragma unroll
        for (int j = 0; j < 4; ++j) a[j] = make_float2(bf2f(au[j]), bf2f_hi(au[j]));
    }
    float2 acc[4] = {{0.f, 0.f}, {0.f, 0.f}, {0.f, 0.f}, {0.f, 0.f}};
    const ushort* cb = col2 + (size_t)n * CAP;
    int deg = degp[n * PADC];
    int eMain = deg & ~7;
    for (int eb = 0; eb < eMain; eb += 8) {
        int sA = cb[eb + lg];
        int sB = cb[eb + lg + 4];
        uint4 bA = *reinterpret_cast<const uint4*>(AB + (size_t)sA * 256 + 128 + fs * 8);
        uint4 bB = *reinterpret_cast<const uint4*>(AB + (size_t)sB * 256 + 128 + fs * 8);
        accum8(bA, a, acc);
        accum8(bB, a, acc);
    }
    for (int e = eMain + lg; e < deg; e += 4) {
        int s = cb[e];
        uint4 b = *reinterpret_cast<const uint4*>(AB + (size_t)s * 256 + 128 + fs * 8);
        accum8(b, a, acc);
    }
#pragma unroll
    for (int j = 0; j < 4; ++j) {
        acc[j].x += __shfl_xor(acc[j].x, 16);
        acc[j].y += __shfl_xor(acc[j].y, 16);
        acc[j].x += __shfl_xor(acc[j].x, 32);
        acc[j].y += __shfl_xor(acc[j].y, 32);
    }
    if (lg == 0) {
        uint4 o;
        uint* ou = reinterpret_cast<uint*>(&o);
#pragma unroll
        for (int j = 0; j < 4; ++j)
            ou[j] = (uint)f2bf(acc[j].x) | ((uint)f2bf(acc[j].y) << 16);
        *reinterpret_cast<uint4*>(Hagg + (size_t)n * 128 + fs * 8) = o;
    }
}

// ---------------- kernels ----------------
__global__ __launch_bounds__(256) void setup_k(
    const float* __restrict__ w1_1, const float* __restrict__ w2_1,
    const float* __restrict__ w1_2, const float* __restrict__ w2_2,
    const float* __restrict__ b1_1, const float* __restrict__ b2_1,
    ushort* __restrict__ wt1a, ushort* __restrict__ wt1b,
    ushort* __restrict__ wt2a, ushort* __restrict__ wt2b,
    float* __restrict__ b256_1, float* __restrict__ b256_2,
    int* __restrict__ degp, float* __restrict__ psum,
    const int* __restrict__ batch, int* __restrict__ gs, int M, int nbDeg) {
    int b = blockIdx.x, t = threadIdx.x;
    if (b < 128) {
        int i = b * 256 + t;
        int j = i >> 7, k = i & 127;
        wt1a[i] = f2bf((j < 128) ? w1_1[k * 128 + j] : w1_1[(128 + k) * 128 + (j - 128)]);
        wt1b[i] = f2bf((j < 128) ? w2_1[k * 128 + j] : w2_1[(128 + k) * 128 + (j - 128)]);
        return;
    }
    b -= 128;
    if (b < 64) {
        int i = b * 256 + t;
        int j = i >> 7, k = i & 127;
        wt2a[i] = f2bf(w1_2[k * 128 + j]);
        wt2b[i] = f2bf(w2_2[k * 128 + j]);
        return;
    }
    b -= 64;
    if (b < nbDeg) {
        int i = b * 256 + t;
        if (i < M) *reinterpret_cast<int4*>(degp + i * PADC) = make_int4(0, 0, 0, 0);
        return;
    }
    b -= nbDeg;
    if (b < 32) {
        psum[b * 256 + t] = 0.f;
        return;
    }
    b -= 32;
    if (b == 0) {
        b256_1[t] = (t < 128) ? b1_1[t] : 0.f;
        b256_2[t] = (t < 128) ? b2_1[t] : 0.f;
        return;
    }
    if (t > GRAPHS) return;
    int lo = 0, hi = M;
    while (lo < hi) {
        int mid = (lo + hi) >> 1;
        if (batch[mid] < t) lo = mid + 1;
        else hi = mid;
    }
    gs[t] = lo;
}

// XCD-partitioned ELL fill (blocks [0,FB)) || layer1 edge-GEMM (blocks [FB, FB+M/64)).
// Fill group s = blockIdx%8 scans ALL edges, commits only dst in node-range s.
__global__ __launch_bounds__(256) void fillgemm_k(const int* __restrict__ src, const int* __restrict__ dst,
                                                  int* __restrict__ degp, ushort* __restrict__ col2,
                                                  int E, int FB, int M,
                                                  const float* __restrict__ x,
                                                  const ushort* __restrict__ wt1a,
                                                  const float* __restrict__ b256_1,
                                                  ushort* __restrict__ AB1) {
    __shared__ SM sm;
    int b = blockIdx.x;
    if (b < FB) {
        int slot = b & 7;
        int grp = b >> 3;
        int nlo = (int)(((long)slot * M) >> 3);
        int nhi = (int)(((long)(slot + 1) * M) >> 3);
        int stride = (FB >> 3) * 256;
        for (int i = grp * 256 + threadIdx.x; i < E; i += stride) {
            int d = dst[i];
            if (d >= nlo && d < nhi) {
                int ticket = atomicAdd(&degp[d * PADC], 1);
                if (ticket < CAP) col2[(size_t)d * CAP + ticket] = (ushort)src[i];
            }
        }
        return;
    }
    ngemm_tile<256, false, false, true>(sm, x, wt1a, b256_1, nullptr, AB1, (b - FB) * 64);
}

__global__ __launch_bounds__(256) void agg_g(const ushort* __restrict__ AB, const int* __restrict__ degp,
                                             const ushort* __restrict__ col2, ushort* __restrict__ Hagg,
                                             int M) {
    int lane = threadIdx.x & 63, wv = threadIdx.x >> 6;
    int n = blockIdx.x * 4 + wv;
    if (n < M) agg_node(AB, degp, col2, Hagg, n, lane);
}

__global__ __launch_bounds__(256) void layer_g(const ushort* __restrict__ Hagg,
                                               const ushort* __restrict__ W2t, const float* __restrict__ b2,
                                               const ushort* __restrict__ W1n, const float* __restrict__ bn,
                                               const int* __restrict__ degp, ushort* __restrict__ AB2) {
    __shared__ SM sm;
    layer_tile(sm, Hagg, W2t, b2, W1n, bn, degp, AB2, blockIdx.x * 64);
}

// H2-GEMM + fused mean-pool partials (two-accumulator boundary handling).
__global__ __launch_bounds__(256) void h2pool_k(const ushort* __restrict__ Hagg,
                                                const ushort* __restrict__ Wt, const float* __restrict__ bias,
                                                const int* __restrict__ degp, const int* __restrict__ batch,
                                                float* __restrict__ psum) {
    __shared__ SM sm;
    int node0 = blockIdx.x * 64;
    stage_tile<false>(sm, Hagg, node0);
    __syncthreads();

    int t = threadIdx.x;
    int lane = t & 63, wv = t >> 6;
    int lr = lane & 15, lg = lane >> 4;

    bf16x8 bfr[4][4];
#pragma unroll
    for (int rs = 0; rs < 4; ++rs)
#pragma unroll
        for (int kk = 0; kk < 4; ++kk)
            bfr[rs][kk] = *reinterpret_cast<const bf16x8*>(&sm.xt[(rs * 16 + lr) * 17 + lg + 4 * kk]);

    float degf[4];
    int gnode[4];
#pragma unroll
    for (int rs = 0; rs < 4; ++rs) {
        int r_ = node0 + rs * 16 + lr;
        degf[rs] = (float)degp[r_ * PADC];
        gnode[rs] = batch[r_];
    }

    int gLo = batch[node0], gHi = batch[node0 + 63];
    bool two = (gHi - gLo) <= 1;

    float sLo[2][4], sHi[2][4];
#pragma unroll
    for (int q = 0; q < 2; ++q)
#pragma unroll
        for (int r = 0; r < 4; ++r) { sLo[q][r] = 0.f; sHi[q][r] = 0.f; }

#pragma unroll
    for (int q = 0; q < 2; ++q) {
        int nb = wv * 2 + q;
        const ushort* wrow = Wt + (size_t)(nb * 16 + lr) * 128 + lg * 8;
        bf16x8 af[4];
#pragma unroll
        for (int kk = 0; kk < 4; ++kk) af[kk] = *reinterpret_cast<const bf16x8*>(wrow + kk * 32);
        float4 bb = *reinterpret_cast<const float4*>(bias + nb * 16 + lg * 4);
        const float* bbp = reinterpret_cast<const float*>(&bb);
#pragma unroll
        for (int rs = 0; rs < 4; ++rs) {
            f32x4 acc = {0.f, 0.f, 0.f, 0.f};
#pragma unroll
            for (int kk = 0; kk < 4; ++kk)
                acc = __builtin_amdgcn_mfma_f32_16x16x32_bf16(af[kk], bfr[rs][kk], acc, 0, 0, 0);
            if (two) {
                bool isLo = (gnode[rs] == gLo);
#pragma unroll
                for (int r = 0; r < 4; ++r) {
                    float v = fmaxf(acc[r] + degf[rs] * bbp[r], 0.f);
                    if (isLo) sLo[q][r] += v;
                    else      sHi[q][r] += v;
                }
            } else {
#pragma unroll
                for (int r = 0; r < 4; ++r) {
                    float v = fmaxf(acc[r] + degf[rs] * bbp[r], 0.f);
                    atomicAdd(&psum[gnode[rs] * 128 + nb * 16 + lg * 4 + r], v);
                }
            }
        }
    }
    if (two) {
        bool split = (gHi != gLo);
#pragma unroll
        for (int q = 0; q < 2; ++q)
#pragma unroll
            for (int r = 0; r < 4; ++r) {
#pragma unroll
                for (int d = 1; d <= 8; d <<= 1) {
                    sLo[q][r] += __shfl_xor(sLo[q][r], d);
                    if (split) sHi[q][r] += __shfl_xor(sHi[q][r], d);
                }
            }
        if (lr == 0) {
#pragma unroll
            for (int q = 0; q < 2; ++q)
#pragma unroll
                for (int r = 0; r < 4; ++r) {
                    int f = (wv * 2 + q) * 16 + lg * 4 + r;
                    atomicAdd(&psum[gLo * 128 + f], sLo[q][r]);
                    if (split) atomicAdd(&psum[gHi * 128 + f], sHi[q][r]);
                }
        }
    }
}

__global__ __launch_bounds__(256) void head_g(const float* __restrict__ psum, const int* __restrict__ gs,
                                              const float* __restrict__ wm1, const float* __restrict__ bm1,
                                              const float* __restrict__ wm2, const float* __restrict__ bm2,
                                              float* __restrict__ out) {
    __shared__ SM sm;
    int g = blockIdx.x, t = threadIdx.x;
    int cnt = gs[g + 1] - gs[g];
    float rcp = 1.0f / (float)(cnt > 0 ? cnt : 1);
    if (t < 128) sm.hd.p[t] = psum[g * 128 + t] * rcp;
    __syncthreads();
    if (t < 128) {
        float a = bm1[t];
        for (int k = 0; k < 128; ++k) a += sm.hd.p[k] * wm1[k * 128 + t];
        sm.hd.h[t] = fmaxf(a, 0.f);
    }
    __syncthreads();
    if (t < 128) {
        float acc[4];
#pragma unroll
        for (int j = 0; j < 4; ++j) acc[j] = bm2[j * 128 + t];
        for (int k = 0; k < 128; ++k) {
            float hv = sm.hd.h[k];
#pragma unroll
            for (int j = 0; j < 4; ++j) acc[j] += hv * wm2[k * 512 + j * 128 + t];
        }
#pragma unroll
        for (int j = 0; j < 4; ++j) out[(size_t)g * 512 + j * 128 + t] = acc[j];
    }
}

extern "C" void kernel_launch(void* const* d_in, const int* in_sizes, int n_in,
                              void* d_out, int out_size, void* d_ws, size_t ws_size,
                              hipStream_t stream) {
    const float* x = (const float*)d_in[0];
    const int* ei = (const int*)d_in[1];
    const int* batch = (const int*)d_in[2];
    const float* w1_1 = (const float*)d_in[3];
    const float* b1_1 = (const float*)d_in[4];
    const float* w1_2 = (const float*)d_in[5];
    const float* b1_2 = (const float*)d_in[6];
    const float* w2_1 = (const float*)d_in[7];
    const float* b2_1 = (const float*)d_in[8];
    const float* w2_2 = (const float*)d_in[9];
    const float* b2_2 = (const float*)d_in[10];
    const float* wm1 = (const float*)d_in[11];
    const float* bm1 = (const float*)d_in[12];
    const float* wm2 = (const float*)d_in[13];
    const float* bm2 = (const float*)d_in[14];

    const int E = in_sizes[1] / 2;
    const int M = in_sizes[0] / 128;
    const int* srcp = ei;
    const int* dstp = ei + E;

    char* ws = (char*)d_ws;
    size_t off = 0;
    auto alloc = [&](size_t bytes) -> void* {
        void* ptr = ws + off;
        off += (bytes + 255) & ~(size_t)255;
        return ptr;
    };
    ushort* AB1 = (ushort*)alloc((size_t)M * 256 * 2);
    ushort* AB2 = (ushort*)alloc((size_t)M * 256 * 2);
    ushort* Hagg = (ushort*)alloc((size_t)M * 128 * 2);
    int* degp = (int*)alloc((size_t)M * PADC * 4);      // padded deg/ticket counters
    ushort* col2 = (ushort*)alloc((size_t)M * CAP * 2); // ELL adjacency (ushort ids)
    int* gs = (int*)alloc((GRAPHS + 1) * 4);
    float* psum = (float*)alloc(GRAPHS * 128 * 4);
    ushort* wt1a = (ushort*)alloc(256 * 128 * 2);
    ushort* wt1b = (ushort*)alloc(256 * 128 * 2);
    ushort* wt2a = (ushort*)alloc(128 * 128 * 2);
    ushort* wt2b = (ushort*)alloc(128 * 128 * 2);
    float* b256_1 = (float*)alloc(256 * 4);
    float* b256_2 = (float*)alloc(256 * 4);

    const int nbDeg = (M + 255) / 256;
    const int FB = 1024;

    // 1. setup (weights, degp=0, psum=0, biases, gstart)
    setup_k<<<128 + 64 + nbDeg + 32 + 2, 256, 0, stream>>>(
        w1_1, w2_1, w1_2, w2_2, b1_1, b2_1, wt1a, wt1b, wt2a, wt2b, b256_1, b256_2,
        degp, psum, batch, gs, M, nbDeg);
    // 2. XCD-partitioned ELL fill || layer1 edge-GEMM
    fillgemm_k<<<FB + M / 64, 256, 0, stream>>>(srcp, dstp, degp, col2, E, FB, M,
                                                x, wt1a, b256_1, AB1);
    // 3. agg layer1
    agg_g<<<(M + 3) / 4, 256, 0, stream>>>(AB1, degp, col2, Hagg, M);
    // 4. fused H1-GEMM + layer2 edge-GEMM
    layer_g<<<M / 64, 256, 0, stream>>>(Hagg, wt2a, b1_2, wt1b, b256_2, degp, AB2);
    // 5. agg layer2
    agg_g<<<(M + 3) / 4, 256, 0, stream>>>(AB2, degp, col2, Hagg, M);
    // 6. H2-GEMM + fused pool
    h2pool_k<<<M / 64, 256, 0, stream>>>(Hagg, wt2b, b2_2, degp, batch, psum);
    // 7. head
    head_g<<<GRAPHS, 256, 0, stream>>>(psum, gs, wm1, bm1, wm2, bm2, (float*)d_out);
}